// Round 13
// baseline (38.842 us; speedup 1.0000x reference)
//
#include <hip/hip_runtime.h>
#include <math.h>

namespace {

constexpr int Bn = 2, Hn = 128, Wn = 128, Cn = 256, Vn = 64;

__device__ __forceinline__ void load8(float* r, const float* p) {
    float4 a = *(const float4*)(p);
    float4 b = *(const float4*)(p + 4);
    r[0]=a.x; r[1]=a.y; r[2]=a.z; r[3]=a.w;
    r[4]=b.x; r[5]=b.y; r[6]=b.z; r[7]=b.w;
}

// DPP-based add of a row-permuted copy (VALU pipe, not DS). CTRL is a
// compile-time template arg. 0xB1=xor1, 0x4E=xor2, 0x124=row_ror:4,
// 0x128=row_ror:8.
template <int CTRL>
__device__ __forceinline__ float row_add(float v) {
    int sh = __builtin_amdgcn_update_dpp(0, __float_as_int(v), CTRL, 0xF, 0xF, true);
    return v + __int_as_float(sh);
}

// Sum over the 32 split lanes (lane bits 0..4), result in all lanes.
// 4 DPP adds (VALU) + ONE ds_swizzle xor16 (DS) — R12-proven.
__device__ __forceinline__ float split_reduce(float v) {
    v = row_add<0xB1>(v);
    v = row_add<0x4E>(v);
    v = row_add<0x124>(v);
    v = row_add<0x128>(v);
    v += __int_as_float(__builtin_amdgcn_ds_swizzle(__float_as_int(v), 0x401F)); // xor16
    return v;
}

// 128 thr = 4 groups x 32 channel-splits; each group owns 4 adjacent pixels.
// R12 (35.5us, VGPR 56) was L1-bytes-bound (~16us of ~620MB through L1).
// 4-px blocking shares 8 window columns among 4 pixels: score bytes/px/di
// 3KB -> 2KB, value 0.75 -> 0.5KB (total ~620 -> ~420MB). Everything else is
// the R12-proven skeleton: rolled di, online softmax seeded by self slot,
// DPP+swizzle reduce, exec-mask predication, grid 2048 (8 segs/row keeps the
// XCD h-mapping that R5 proved essential). Target VGPR <=128 (4-wave bin).
__global__ __launch_bounds__(128)
void local_attn_kernel(const float* __restrict__ mainp,
                       const float* __restrict__ mainv,
                       const float* __restrict__ refp,
                       const float* __restrict__ refv,
                       float* __restrict__ outp)
{
    const int t = threadIdx.x;  // 0..127
    const int s = t & 31;       // channel split 0..31 (8 ch each)
    const int g = t >> 5;       // group 0..3 (4 px each)
    const int blk = blockIdx.x; // 0 .. 2047
    const int seg = blk & 7;
    const int h   = (blk >> 3) & (Hn - 1);
    const int b   = blk >> 10;
    const int w0  = seg * 16 + g * 4;   // group pixels w0 .. w0+3
    const int rowbase = b * Hn + h;

    // main channels: 8 per pixel (ch = s*8 .. s*8+7)
    float m[4][8];
    const float* mp = mainp + ((size_t)rowbase * Wn + w0) * Cn + s * 8;
    #pragma unroll
    for (int p = 0; p < 4; ++p) load8(m[p], mp + (size_t)p * Cn);

    // self scores (slot 25)
    float mx[4], den[4];
    #pragma unroll
    for (int p = 0; p < 4; ++p) {
        float sf = 0.f;
        #pragma unroll
        for (int c = 0; c < 8; ++c) sf = fmaf(m[p][c], m[p][c], sf);
        mx[p] = split_reduce(sf);   // online state seeded with self (w=1)
        den[p] = 1.f;
    }

    float acc[4][2];
    {
        const float* mvp = mainv + ((size_t)rowbase * Wn + w0) * Vn + s * 2;
        #pragma unroll
        for (int p = 0; p < 4; ++p) {
            float2 a = *(const float2*)(mvp + (size_t)p * Vn);
            acc[p][0] = a.x; acc[p][1] = a.y;
        }
    }

    #pragma unroll 1
    for (int di = 0; di < 5; ++di) {
        const int hh = h + di - 2;
        const bool rowok = (unsigned)hh < (unsigned)Hn;
        const size_t rbase = (size_t)(b * Hn + (rowok ? hh : 0)) * Wn;
        const float* rp = refp + rbase * Cn + s * 8;

        // ---- scores: 8 shared column loads serve 4 pixels ----
        float sc[4][5];
        #pragma unroll
        for (int o = 0; o < 8; ++o) {
            const int col = w0 - 2 + o;
            const bool ok = rowok && (unsigned)col < (unsigned)Wn;
            float r[8];
            #pragma unroll
            for (int c = 0; c < 8; ++c) r[c] = 0.f;
            if (ok) load8(r, rp + (size_t)col * Cn);
            #pragma unroll
            for (int p = 0; p < 4; ++p) {
                if (o >= p && o <= p + 4) {      // compile-time per (o,p)
                    float a = 0.f;
                    #pragma unroll
                    for (int c = 0; c < 8; ++c) a = fmaf(m[p][c], r[c], a);
                    sc[p][o - p] = a;
                }
            }
        }

        // reduce partial dots across the 32 split lanes
        #pragma unroll
        for (int p = 0; p < 4; ++p)
            #pragma unroll
            for (int k = 0; k < 5; ++k)
                sc[p][k] = split_reduce(sc[p][k]);

        // ---- online softmax row update (4 pixels) ----
        #pragma unroll
        for (int p = 0; p < 4; ++p) {
            const float rm = fmaxf(fmaxf(fmaxf(sc[p][0], sc[p][1]),
                                         fmaxf(sc[p][2], sc[p][3])), sc[p][4]);
            const float nm = fmaxf(mx[p], rm);
            const float e  = __expf(mx[p] - nm);
            float sum = 0.f;
            #pragma unroll
            for (int k = 0; k < 5; ++k) { sc[p][k] = __expf(sc[p][k] - nm); sum += sc[p][k]; }
            den[p] = den[p] * e + sum;
            acc[p][0] *= e; acc[p][1] *= e;
            mx[p] = nm;
        }

        // ---- values: 8 shared float2 column loads serve 4 pixels ----
        const float* rvp = refv + rbase * Vn + s * 2;
        #pragma unroll
        for (int o = 0; o < 8; ++o) {
            const int col = w0 - 2 + o;
            float2 rv = make_float2(0.f, 0.f);
            if (rowok && (unsigned)col < (unsigned)Wn)
                rv = *(const float2*)(rvp + (size_t)col * Vn);
            #pragma unroll
            for (int p = 0; p < 4; ++p) {
                if (o >= p && o <= p + 4) {
                    const float wkj = sc[p][o - p];
                    acc[p][0] = fmaf(wkj, rv.x, acc[p][0]);
                    acc[p][1] = fmaf(wkj, rv.y, acc[p][1]);
                }
            }
        }
    }

    float* op = outp + ((size_t)rowbase * Wn + w0) * Vn + s * 2;
    #pragma unroll
    for (int p = 0; p < 4; ++p) {
        const float inv = 1.f / den[p];
        float2 o;
        o.x = acc[p][0] * inv; o.y = acc[p][1] * inv;
        *(float2*)(op + (size_t)p * Vn) = o;
    }
}

} // namespace

extern "C" void kernel_launch(void* const* d_in, const int* in_sizes, int n_in,
                              void* d_out, int out_size, void* d_ws, size_t ws_size,
                              hipStream_t stream)
{
    const float* mainp = (const float*)d_in[0];
    const float* mainv = (const float*)d_in[1];
    const float* refp  = (const float*)d_in[2];
    const float* refv  = (const float*)d_in[3];
    float* outp = (float*)d_out;

    dim3 grid(Bn * Hn * 8);   // 2048 blocks: one per 16-pixel row segment
    dim3 block(128);          // 4 groups x 32 splits
    hipLaunchKernelGGL(local_attn_kernel, grid, block, 0, stream,
                       mainp, mainv, refp, refv, outp);
}

// Round 14
// 35.995 us; speedup vs baseline: 1.0791x; 1.0791x over previous
//
#include <hip/hip_runtime.h>
#include <math.h>

namespace {

constexpr int Bn = 2, Hn = 128, Wn = 128, Cn = 256, Vn = 64;

__device__ __forceinline__ void load8(float* r, const float* p) {
    float4 a = *(const float4*)(p);
    float4 b = *(const float4*)(p + 4);
    r[0]=a.x; r[1]=a.y; r[2]=a.z; r[3]=a.w;
    r[4]=b.x; r[5]=b.y; r[6]=b.z; r[7]=b.w;
}

// DPP-based add of a row-permuted copy (VALU pipe, not DS). CTRL is a
// compile-time template arg. 0xB1=xor1, 0x4E=xor2, 0x124=row_ror:4,
// 0x128=row_ror:8.
template <int CTRL>
__device__ __forceinline__ float row_add(float v) {
    int sh = __builtin_amdgcn_update_dpp(0, __float_as_int(v), CTRL, 0xF, 0xF, true);
    return v + __int_as_float(sh);
}

// Sum over the 32 split lanes (lane bits 0..4), result in all lanes.
// 4 DPP adds (VALU) + ONE ds_swizzle xor16 (DS) — R12-proven.
__device__ __forceinline__ float split_reduce(float v) {
    v = row_add<0xB1>(v);
    v = row_add<0x4E>(v);
    v = row_add<0x124>(v);
    v = row_add<0x128>(v);
    v += __int_as_float(__builtin_amdgcn_ds_swizzle(__float_as_int(v), 0x401F)); // xor16
    return v;
}

__device__ __forceinline__ int clampc(int c, int lo, int hi) {
    return c < lo ? lo : (c > hi ? hi : c);
}

// 256 thr = 8 pixel-PAIRS x 32 channel-splits (R12 winner, 35.5us) with ONE
// change: clamp-and-mask-late instead of per-element exec-mask predication.
// All ref/refv loads are UNCONDITIONAL from clamped addresses (garbage for
// OOB slots); correctness is restored by (a) zeroing the 10 scores post-
// reduce (OOB slot score must be exactly 0 -> weight exp(0-nm) stays in the
// denominator, matching the reference's zero-padding) and (b) zeroing the 10
// value-weights post-exp (OOB value is 0). Removes ~50 VALU/di of r-zeroing
// + mask setup and lets the compiler hoist/cluster loads across the softmax.
__global__ __launch_bounds__(256)
void local_attn_kernel(const float* __restrict__ mainp,
                       const float* __restrict__ mainv,
                       const float* __restrict__ refp,
                       const float* __restrict__ refv,
                       float* __restrict__ outp)
{
    const int t = threadIdx.x;
    const int s = t & 31;       // channel split 0..31 (8 ch each)
    const int g = t >> 5;       // pixel-pair 0..7
    const int blk = blockIdx.x; // 0 .. 2047
    const int seg = blk & 7;
    const int h   = (blk >> 3) & (Hn - 1);
    const int b   = blk >> 10;
    const int w0  = seg * 16 + g * 2;   // px0 = w0, px1 = w0+1
    const int rowbase = b * Hn + h;

    // main channels: 8 each for px0/px1 (ch = s*8 .. s*8+7)
    float m0[8], m1[8];
    const float* mp = mainp + ((size_t)rowbase * Wn + w0) * Cn + s * 8;
    load8(m0, mp);
    load8(m1, mp + Cn);

    // self scores (slot 25)
    float self0 = 0.f, self1 = 0.f;
    #pragma unroll
    for (int c = 0; c < 8; ++c) {
        self0 = fmaf(m0[c], m0[c], self0);
        self1 = fmaf(m1[c], m1[c], self1);
    }
    self0 = split_reduce(self0);
    self1 = split_reduce(self1);

    // online-softmax state seeded with the self slot (weight exp(0)=1)
    float mx0 = self0, mx1 = self1, den0 = 1.f, den1 = 1.f;
    float acc0[2], acc1[2];
    {
        const float* mvp = mainv + ((size_t)rowbase * Wn + w0) * Vn + s * 2;
        float2 a = *(const float2*)(mvp);
        float2 c = *(const float2*)(mvp + Vn);
        acc0[0] = a.x; acc0[1] = a.y;
        acc1[0] = c.x; acc1[1] = c.y;
    }

    #pragma unroll 1
    for (int di = 0; di < 5; ++di) {
        const int hh = h + di - 2;
        const bool rowok = (unsigned)hh < (unsigned)Hn;
        const int hhc = clampc(hh, 0, Hn - 1);
        const size_t rbase = (size_t)(b * Hn + hhc) * Wn;
        const float* rp = refp + rbase * Cn + s * 8;

        // ---- scores: 6 shared UNCONDITIONAL column loads (clamped addr) ----
        float sc0[5], sc1[5];
        #pragma unroll
        for (int o = 0; o < 6; ++o) {
            const int colc = clampc(w0 - 2 + o, 0, Wn - 1);
            float r[8];
            load8(r, rp + (size_t)colc * Cn);
            if (o < 5) {
                float a = 0.f;
                #pragma unroll
                for (int c = 0; c < 8; ++c) a = fmaf(m0[c], r[c], a);
                sc0[o] = a;
            }
            if (o >= 1) {
                float a = 0.f;
                #pragma unroll
                for (int c = 0; c < 8; ++c) a = fmaf(m1[c], r[c], a);
                sc1[o - 1] = a;
            }
        }

        // reduce partial dots across the 32 split lanes
        #pragma unroll
        for (int k = 0; k < 5; ++k) {
            sc0[k] = split_reduce(sc0[k]);
            sc1[k] = split_reduce(sc1[k]);
        }

        // ---- mask OOB slots to score 0 (reference zero-pad semantics) ----
        #pragma unroll
        for (int k = 0; k < 5; ++k) {
            const bool ok0 = rowok && (unsigned)(w0 - 2 + k) < (unsigned)Wn;
            const bool ok1 = rowok && (unsigned)(w0 - 1 + k) < (unsigned)Wn;
            sc0[k] = ok0 ? sc0[k] : 0.f;
            sc1[k] = ok1 ? sc1[k] : 0.f;
        }

        // ---- online softmax row update (both pixels)
        const float rm0 = fmaxf(fmaxf(fmaxf(sc0[0], sc0[1]), fmaxf(sc0[2], sc0[3])), sc0[4]);
        const float rm1 = fmaxf(fmaxf(fmaxf(sc1[0], sc1[1]), fmaxf(sc1[2], sc1[3])), sc1[4]);
        const float nm0 = fmaxf(mx0, rm0), nm1 = fmaxf(mx1, rm1);
        const float e0 = __expf(mx0 - nm0), e1 = __expf(mx1 - nm1);
        float sum0 = 0.f, sum1 = 0.f;
        #pragma unroll
        for (int k = 0; k < 5; ++k) {
            sc0[k] = __expf(sc0[k] - nm0); sum0 += sc0[k];
            sc1[k] = __expf(sc1[k] - nm1); sum1 += sc1[k];
        }
        den0 = den0 * e0 + sum0;
        den1 = den1 * e1 + sum1;
        acc0[0] *= e0; acc0[1] *= e0;
        acc1[0] *= e1; acc1[1] *= e1;
        mx0 = nm0; mx1 = nm1;

        // ---- value-weights: OOB slots contribute 0 value (keep den intact)
        float wu0[5], wu1[5];
        #pragma unroll
        for (int k = 0; k < 5; ++k) {
            const bool ok0 = rowok && (unsigned)(w0 - 2 + k) < (unsigned)Wn;
            const bool ok1 = rowok && (unsigned)(w0 - 1 + k) < (unsigned)Wn;
            wu0[k] = ok0 ? sc0[k] : 0.f;
            wu1[k] = ok1 ? sc1[k] : 0.f;
        }

        // ---- values: 6 shared UNCONDITIONAL float2 loads (clamped addr) ----
        const float* rvp = refv + rbase * Vn + s * 2;
        #pragma unroll
        for (int o = 0; o < 6; ++o) {
            const int colc = clampc(w0 - 2 + o, 0, Wn - 1);
            float2 rv = *(const float2*)(rvp + (size_t)colc * Vn);
            if (o < 5) {
                acc0[0] = fmaf(wu0[o], rv.x, acc0[0]);
                acc0[1] = fmaf(wu0[o], rv.y, acc0[1]);
            }
            if (o >= 1) {
                acc1[0] = fmaf(wu1[o - 1], rv.x, acc1[0]);
                acc1[1] = fmaf(wu1[o - 1], rv.y, acc1[1]);
            }
        }
    }

    const float inv0 = 1.f / den0, inv1 = 1.f / den1;
    float* op = outp + ((size_t)rowbase * Wn + w0) * Vn + s * 2;
    float2 o0, o1;
    o0.x = acc0[0] * inv0; o0.y = acc0[1] * inv0;
    o1.x = acc1[0] * inv1; o1.y = acc1[1] * inv1;
    *(float2*)(op)      = o0;
    *(float2*)(op + Vn) = o1;
}

} // namespace

extern "C" void kernel_launch(void* const* d_in, const int* in_sizes, int n_in,
                              void* d_out, int out_size, void* d_ws, size_t ws_size,
                              hipStream_t stream)
{
    const float* mainp = (const float*)d_in[0];
    const float* mainv = (const float*)d_in[1];
    const float* refp  = (const float*)d_in[2];
    const float* refv  = (const float*)d_in[3];
    float* outp = (float*)d_out;

    dim3 grid(Bn * Hn * 8);   // 2048 blocks: one per 16-pixel row segment
    dim3 block(256);          // 8 pairs x 32 splits
    hipLaunchKernelGGL(local_attn_kernel, grid, block, 0, stream,
                       mainp, mainv, refp, refv, outp);
}